// Round 3
// baseline (417.321 us; speedup 1.0000x reference)
//
#include <hip/hip_runtime.h>
#include <hip/hip_bf16.h>

// Problem constants
#define B_    32
#define H_    64
#define W_    64
#define C_    256
#define NH_   8
#define N_    16
#define PIX_  (B_*H_*W_)     // 131072
#define OUTPIX_ (B_*32*32)   // 32768

typedef __hip_bfloat16 bf16;
typedef __attribute__((ext_vector_type(8))) short bf16x8;   // 8 bf16 = 4 VGPR
typedef __attribute__((ext_vector_type(4))) float f32x4;

__device__ __forceinline__ float bf2f(unsigned short u) {
  union { unsigned int i; float f; } v; v.i = ((unsigned int)u) << 16; return v.f;
}
__device__ __forceinline__ unsigned pk2(float a, float b) {
  union { __hip_bfloat162 h2; unsigned u; } c;
  c.h2 = __float22bfloat162_rn(make_float2(a, b));
  return c.u;
}
// 8 consecutive fp32 -> bf16x8 (same rounding as the original staging path)
__device__ __forceinline__ bf16x8 cvt8(float4 lo, float4 hi) {
  union { bf16x8 v; unsigned u[4]; } r;
  r.u[0] = pk2(lo.x, lo.y); r.u[1] = pk2(lo.z, lo.w);
  r.u[2] = pk2(hi.x, hi.y); r.u[3] = pk2(hi.z, hi.w);
  return r.v;
}
// async HBM->LDS, 16 B per lane; LDS dest is wave-uniform base + lane*16
__device__ __forceinline__ void async_copy16(void* lds, const void* g) {
  __builtin_amdgcn_global_load_lds(
      (const __attribute__((address_space(1))) unsigned int*)g,
      (__attribute__((address_space(3))) unsigned int*)lds, 16, 0, 0);
}

// ---------------------------------------------------------------------------
// K1: s0[8][16] (softmax row 0 of logits) and qv[8]. One block.
// ---------------------------------------------------------------------------
__global__ __launch_bounds__(256) void k1_setup(
    const float* __restrict__ emb, const float* __restrict__ wkq_w,
    const float* __restrict__ wkq_b, const float* __restrict__ wgq_w,
    const float* __restrict__ wgq_b,
    float* __restrict__ s0, float* __restrict__ qv) {
  __shared__ float lq[128];
  __shared__ float lk[16][8];
  int t = threadIdx.x;
  if (t < 128) {
    float acc = wkq_b[128 + t];
    for (int e = 0; e < 128; ++e) acc += emb[e] * wkq_w[e * 256 + 128 + t];
    lq[t] = acc;
  } else {
    int idx = t - 128; int j = idx >> 3, h = idx & 7;
    float acc = wkq_b[h * 16];
    for (int e = 0; e < 128; ++e) acc += emb[j * 128 + e] * wkq_w[e * 256 + h * 16];
    lk[j][h] = acc;
  }
  __syncthreads();
  if (t < 8) {
    float l[16]; float m = -1e30f;
    for (int j = 0; j < 16; ++j) { l[j] = lq[t * 16 + j] + lk[j][t]; m = fmaxf(m, l[j]); }
    float s = 0.f;
    for (int j = 0; j < 16; ++j) { l[j] = expf(l[j] - m); s += l[j]; }
    float inv = 1.f / s;
    for (int j = 0; j < 16; ++j) s0[t * 16 + j] = l[j] * inv;
    float acc = wgq_b[t];
    for (int e = 0; e < 128; ++e) acc += emb[14 * 128 + e] * wgq_w[e * 8 + t];
    qv[t] = acc;
  }
}

// ---------------------------------------------------------------------------
// prep: LDS-tiled transposes to bf16.
//   blocks 0..15 : wvT[n][k]  = wv[k][n]   (64x64 tiles)
//   blocks 16..31: wfT[n][k]  = wf[k][n]
//   block  32    : wgkT[a][k] = wgk[k][a]  (rows 8..15 zero)
// ---------------------------------------------------------------------------
__global__ __launch_bounds__(256) void prep(
    const float* __restrict__ wv, const float* __restrict__ wf,
    const float* __restrict__ wgk,
    bf16* __restrict__ wvT, bf16* __restrict__ wfT, bf16* __restrict__ wgkT) {
  int bid = blockIdx.x, t = threadIdx.x;
  if (bid < 32) {
    __shared__ unsigned short tile[64][72];
    const float* src = (bid < 16) ? wv : wf;
    bf16* dst = (bid < 16) ? wvT : wfT;
    int tb = bid & 15, tr = tb >> 2, tc = tb & 3;
#pragma unroll
    for (int it = 0; it < 16; ++it) {
      int idx = it * 256 + t, row = idx >> 6, col = idx & 63;
      bf16 h = __float2bfloat16(src[(tr * 64 + row) * 256 + tc * 64 + col]);
      tile[row][col] = *(unsigned short*)&h;
    }
    __syncthreads();
#pragma unroll
    for (int it = 0; it < 16; ++it) {
      int idx = it * 256 + t, row = idx >> 6, col = idx & 63;
      dst[(tc * 64 + row) * 256 + (tr * 64 + col)] = *(bf16*)&tile[col][row];
    }
  } else {
    __shared__ float g[2048];
#pragma unroll
    for (int it = 0; it < 8; ++it) g[it * 256 + t] = wgk[it * 256 + t];
    __syncthreads();
#pragma unroll
    for (int it = 0; it < 16; ++it) {
      int idx = it * 256 + t, a = idx >> 8, k = idx & 255;
      float v = (a < 8) ? g[k * 8 + a] : 0.f;
      wgkT[a * 256 + k] = __float2bfloat16(v);
    }
  }
}

// ---------------------------------------------------------------------------
// kA v4 (global_load_lds pipelined GEMM + fused gate):
//   vraw = inps @ wv + wv_b          (bf16 out, no scale yet)
//   g    = relu(qv + inps @ wgk + b) -> gbuf; denom += sum(g)
// 512 blocks x 4 tiles of 64 px. A staged per half-K (64x128 fp32) into
// double-buffered LDS via global_load_lds width=16 (no staging VGPRs ->
// nothing to spill). Loads for phase p+1 issue at the top of phase p and
// stay in flight under the whole compute phase (m97 structure).
// Source-address XOR swizzle (unit ^= row&7 on 16B units) + matching XOR on
// the ds_read index keeps fragment reads bank-balanced (rule #21).
// fp32->bf16 cvt happens per-fragment in-register (VALU is idle).
// ---------------------------------------------------------------------------
#define KA_TILES 4
__global__ __launch_bounds__(512, 4) void kA(
    const float* __restrict__ inps, const bf16* __restrict__ wvT,
    const bf16* __restrict__ wgkT, const float* __restrict__ wv_b,
    const float* __restrict__ wgk_b, const float* __restrict__ qv,
    bf16* __restrict__ vraw, float* __restrict__ gbuf,
    float* __restrict__ denom) {
  // [2 buffers][64 rows][128 fp32] = 64 KB, linear (gload_lds needs it)
  __shared__ __align__(16) float ldsA[2][64][128];
  __shared__ float sden[8];
  __shared__ float qvb_s[8];
  int t = threadIdx.x;
  int bid = blockIdx.x;
  const long px_base = (long)bid * (KA_TILES * 64);
  if (t < 8) { sden[t] = 0.f; qvb_s[t] = qv[t] + wgk_b[t]; }

  int wave = t >> 6, lane = t & 63;
  int mw = wave >> 2, nw = wave & 3;
  int m0 = mw * 32, n0 = nw * 64;
  int lm = lane & 15, q = lane >> 4;
  bool gatew = (nw == 0);
  const bf16* brow = wvT + (n0 + lm) * 256;
  const bf16* grow = wgkT + lm * 256;

  // staging geometry: wave w covers rows 8w..8w+7 in 4 insts (2 rows/inst);
  // lane supplies global 16B unit (u ^ (row&7)) so LDS row is stored
  // XOR-swizzled while the LDS write itself stays linear.
  const int s_u = lane & 31;          // 16B unit within half-row (0..31)
  const int s_rh = lane >> 5;         // row parity within inst
  // phase ph (0..7): tile ph>>1, K-half ph&1
#define STAGE(ph_, bufi_)                                                     \
  {                                                                           \
    const float* gb_ =                                                        \
        inps + (px_base + ((ph_) >> 1) * 64) * 256 + ((ph_) & 1) * 128;       \
    _Pragma("unroll")                                                         \
    for (int i_ = 0; i_ < 4; ++i_) {                                          \
      int r_ = 8 * wave + 2 * i_ + s_rh;                                      \
      const float* g_ = gb_ + r_ * 256 + ((s_u ^ (r_ & 7)) << 2);             \
      async_copy16(&ldsA[bufi_][8 * wave + 2 * i_][0], g_);                   \
    }                                                                         \
  }

  STAGE(0, 0);
  __syncthreads();               // vmcnt(0) drain before barrier: buf0 ready

  // fragment-read constants
  const float4* pA0 = (const float4*)&ldsA[0][0][0];
  const float4* pA1 = (const float4*)&ldsA[1][0][0];
  const int rx = (m0 + lm) & 7;              // same for row and row+16
  const int i0 = (m0 + lm) * 32;             // float4 units per row = 32
  const int i1 = (m0 + 16 + lm) * 32;

  f32x4 acc[2][4], accg[2];
  float gsum = 0.f;

#pragma unroll 2
  for (int ph = 0; ph < 2 * KA_TILES; ++ph) {
    const int cur = ph & 1;
    if (ph < 2 * KA_TILES - 1) STAGE(ph + 1, cur ^ 1);  // in flight over compute
    if (cur == 0) {
#pragma unroll
      for (int mf = 0; mf < 2; ++mf) {
        accg[mf] = (f32x4){0.f, 0.f, 0.f, 0.f};
#pragma unroll
        for (int nf = 0; nf < 4; ++nf) acc[mf][nf] = (f32x4){0.f, 0.f, 0.f, 0.f};
      }
    }
    const float4* pA = cur ? pA1 : pA0;
#pragma unroll
    for (int ksl = 0; ksl < 4; ++ksl) {
      int ulo = (ksl * 8 + q * 2) ^ rx;      // LDS unit holding global unit u0
      float4 a0lo = pA[i0 + ulo], a0hi = pA[i0 + (ulo ^ 1)];
      float4 a1lo = pA[i1 + ulo], a1hi = pA[i1 + (ulo ^ 1)];
      bf16x8 a0 = cvt8(a0lo, a0hi);
      bf16x8 a1 = cvt8(a1lo, a1hi);
      int gk = cur * 128 + ksl * 32 + q * 8;
      bf16x8 b0 = *(const bf16x8*)(brow + gk);
      bf16x8 b1 = *(const bf16x8*)(brow + 4096 + gk);
      bf16x8 b2 = *(const bf16x8*)(brow + 8192 + gk);
      bf16x8 b3 = *(const bf16x8*)(brow + 12288 + gk);
      acc[0][0] = __builtin_amdgcn_mfma_f32_16x16x32_bf16(a0, b0, acc[0][0], 0, 0, 0);
      acc[1][0] = __builtin_amdgcn_mfma_f32_16x16x32_bf16(a1, b0, acc[1][0], 0, 0, 0);
      acc[0][1] = __builtin_amdgcn_mfma_f32_16x16x32_bf16(a0, b1, acc[0][1], 0, 0, 0);
      acc[1][1] = __builtin_amdgcn_mfma_f32_16x16x32_bf16(a1, b1, acc[1][1], 0, 0, 0);
      acc[0][2] = __builtin_amdgcn_mfma_f32_16x16x32_bf16(a0, b2, acc[0][2], 0, 0, 0);
      acc[1][2] = __builtin_amdgcn_mfma_f32_16x16x32_bf16(a1, b2, acc[1][2], 0, 0, 0);
      acc[0][3] = __builtin_amdgcn_mfma_f32_16x16x32_bf16(a0, b3, acc[0][3], 0, 0, 0);
      acc[1][3] = __builtin_amdgcn_mfma_f32_16x16x32_bf16(a1, b3, acc[1][3], 0, 0, 0);
      if (gatew) {
        bf16x8 bg = *(const bf16x8*)(grow + gk);
        accg[0] = __builtin_amdgcn_mfma_f32_16x16x32_bf16(a0, bg, accg[0], 0, 0, 0);
        accg[1] = __builtin_amdgcn_mfma_f32_16x16x32_bf16(a1, bg, accg[1], 0, 0, 0);
      }
    }

    if (cur == 1) {  // tile complete: epilogues
      long pix0 = px_base + (ph >> 1) * 64;
      // vraw (bias only; scale applied in kB)
#pragma unroll
      for (int nf = 0; nf < 4; ++nf) {
        int col = n0 + nf * 16 + lm;
        float wb = wv_b[col];
#pragma unroll
        for (int mf = 0; mf < 2; ++mf) {
#pragma unroll
          for (int r = 0; r < 4; ++r) {
            int rl = m0 + mf * 16 + q * 4 + r;
            vraw[(pix0 + rl) * 256 + col] = __float2bfloat16(acc[mf][nf][r] + wb);
          }
        }
      }
      // gate: store g, accumulate per-lane partial sum across tiles
      if (gatew && lm < 8) {
#pragma unroll
        for (int mf = 0; mf < 2; ++mf) {
#pragma unroll
          for (int r = 0; r < 4; ++r) {
            int rl = m0 + mf * 16 + q * 4 + r;
            float gg = fmaxf(qvb_s[lm] + accg[mf][r], 0.f);
            gbuf[(pix0 + rl) * 8 + lm] = gg;
            gsum += gg;
          }
        }
      }
    }
    __syncthreads();   // drains this phase's STAGE loads -> next buffer ready
  }

  // gate reduction: one LDS atomic per gate wave, one global atomic per block
  if (gatew) {
    gsum += __shfl_xor(gsum, 16, 64);
    gsum += __shfl_xor(gsum, 32, 64);
    if (lane < 8) atomicAdd(&sden[lane], gsum);
  }
  __syncthreads();
  if (t < 8) atomicAdd(&denom[(bid >> 4) * 8 + t], sden[t]);
#undef STAGE
}

// ---------------------------------------------------------------------------
// kB (fused scale + patch gather + final GEMM). Block = (b,x) row, 256 thr.
// Phase 0: stage scf[i][c][a] = 4096/(denom+eps)*g for the 4 source rows.
// Phase 1: op[y][ch] = sum_taps (s0*scf) * vraw   (uint = 2ch per lane)
// Phase 2: out = op @ wf + wf_b via MFMA (wfT in L2).
// ---------------------------------------------------------------------------
__global__ __launch_bounds__(256) void kB(
    const bf16* __restrict__ vraw, const float* __restrict__ s0,
    const float* __restrict__ gbuf, const float* __restrict__ denom,
    const bf16* __restrict__ wfT, const float* __restrict__ wf_b,
    float* __restrict__ out) {
  __shared__ float scfsh[4][64][8];                      // 8 KB
  __shared__ __align__(16) unsigned short opsh[32][264]; // bf16 bits
  int t = threadIdx.x;
  int bx = blockIdx.x, b = bx >> 5, x = bx & 31;

  { // phase 0
    int i = t >> 6, c = t & 63;
    int r = 2 * x + i - 1;
    if (r >= 0 && r < 64) {
      long p = (long)b * 4096 + r * 64 + c;
#pragma unroll
      for (int a = 0; a < 8; ++a)
        scfsh[i][c][a] = 4096.0f / (denom[b * 8 + a] + 1e-6f) * gbuf[p * 8 + a];
    } else {
#pragma unroll
      for (int a = 0; a < 8; ++a) scfsh[i][c][a] = 0.f;
    }
  }
  __syncthreads();

  // phase 1
  int c2 = t & 127, yg = t >> 7;
  int h = c2 >> 4;
  float s0r[16];
#pragma unroll
  for (int n = 0; n < 16; ++n) s0r[n] = s0[h * 16 + n];
  const bf16* vsb = vraw + (long)b * (4096 * 256);
  for (int yi = 0; yi < 16; ++yi) {
    int y = yi * 2 + yg;
    float p0 = 0.f, p1 = 0.f;
#pragma unroll
    for (int i = 0; i < 4; ++i) {
      int r = 2 * x + i - 1;
      if (r < 0 || r >= 64) continue;               // block-uniform
      const bf16* rowp = vsb + (long)r * 64 * 256 + 2 * c2;
#pragma unroll
      for (int j = 0; j < 4; ++j) {
        int c = 2 * y + j - 1;
        if (c < 0 || c >= 64) continue;             // wave-uniform
        float coef = s0r[i * 4 + j] * scfsh[i][c][h];
        unsigned u = *(const unsigned*)(rowp + (long)c * 256);
        p0 += coef * bf2f((unsigned short)(u & 0xffff));
        p1 += coef * bf2f((unsigned short)(u >> 16));
      }
    }
    *(unsigned*)&opsh[y][2 * c2] = pk2(p0, p1);
  }
  __syncthreads();

  // phase 2: MFMA  out[32x256] = op @ wf + b
  int wave = t >> 6, lane = t & 63;
  int n0 = wave * 64;
  int lm = lane & 15, q = lane >> 4;
  f32x4 acc[2][4];
#pragma unroll
  for (int mf = 0; mf < 2; ++mf)
#pragma unroll
    for (int nf = 0; nf < 4; ++nf) acc[mf][nf] = (f32x4){0.f, 0.f, 0.f, 0.f};
  const bf16* brow = wfT + (n0 + lm) * 256;
#pragma unroll
  for (int ks = 0; ks < 8; ++ks) {
    int kof = ks * 32 + q * 8;
    bf16x8 a0 = *(const bf16x8*)(&opsh[lm][kof]);
    bf16x8 a1 = *(const bf16x8*)(&opsh[16 + lm][kof]);
#pragma unroll
    for (int nf = 0; nf < 4; ++nf) {
      bf16x8 bb = *(const bf16x8*)(brow + nf * 4096 + kof);
      acc[0][nf] = __builtin_amdgcn_mfma_f32_16x16x32_bf16(a0, bb, acc[0][nf], 0, 0, 0);
      acc[1][nf] = __builtin_amdgcn_mfma_f32_16x16x32_bf16(a1, bb, acc[1][nf], 0, 0, 0);
    }
  }
  long out0 = (long)bx * 32 * 256;
#pragma unroll
  for (int nf = 0; nf < 4; ++nf) {
    int col = n0 + nf * 16 + lm;
    float wb = wf_b[col];
#pragma unroll
    for (int mf = 0; mf < 2; ++mf) {
#pragma unroll
      for (int r = 0; r < 4; ++r) {
        int row = mf * 16 + q * 4 + r;
        out[out0 + row * 256 + col] = acc[mf][nf][r] + wb;
      }
    }
  }
}

// ---------------------------------------------------------------------------
// Workspace (float offsets): s0 0 | qv 128 | denom 256 | gbuf 1024 (+1M)
// wvT @1049600 (+32768) | wfT @1082368 (+32768) | wgkT @1115136 (+2048)
// vraw(bf16) @1117184 (+16.7M f-equiv). Total ~71.6 MB.
// ---------------------------------------------------------------------------
extern "C" void kernel_launch(void* const* d_in, const int* in_sizes, int n_in,
                              void* d_out, int out_size, void* d_ws, size_t ws_size,
                              hipStream_t stream) {
  const float* inps  = (const float*)d_in[0];
  const float* emb   = (const float*)d_in[1];
  const float* wkq_w = (const float*)d_in[2];
  const float* wkq_b = (const float*)d_in[3];
  const float* wv_w  = (const float*)d_in[4];
  const float* wv_b  = (const float*)d_in[5];
  const float* wgq_w = (const float*)d_in[6];
  const float* wgq_b = (const float*)d_in[7];
  const float* wgk_w = (const float*)d_in[8];
  const float* wgk_b = (const float*)d_in[9];
  const float* wf_w  = (const float*)d_in[10];
  const float* wf_b  = (const float*)d_in[11];

  float* wsf   = (float*)d_ws;
  float* s0f   = wsf;
  float* qvf   = wsf + 128;
  float* denom = wsf + 256;
  float* gbuf  = wsf + 1024;
  bf16*  wvT   = (bf16*)(wsf + 1049600);
  bf16*  wfT   = (bf16*)(wsf + 1082368);
  bf16*  wgkT  = (bf16*)(wsf + 1115136);
  bf16*  vraw  = (bf16*)(wsf + 1117184);
  float* outp  = (float*)d_out;

  hipMemsetAsync((void*)denom, 0, 1024, stream);
  k1_setup<<<1, 256, 0, stream>>>(emb, wkq_w, wkq_b, wgq_w, wgq_b, s0f, qvf);
  prep<<<33, 256, 0, stream>>>(wv_w, wf_w, wgk_w, wvT, wfT, wgkT);
  kA<<<PIX_ / (KA_TILES * 64), 512, 0, stream>>>(inps, wvT, wgkT, wv_b, wgk_b, qvf,
                                                 vraw, gbuf, denom);
  kB<<<OUTPIX_ / 32, 256, 0, stream>>>(vraw, s0f, gbuf, denom, wfT, wf_b, outp);
}

// Round 4
// 380.784 us; speedup vs baseline: 1.0960x; 1.0960x over previous
//
#include <hip/hip_runtime.h>
#include <hip/hip_bf16.h>

// Problem constants
#define B_    32
#define H_    64
#define W_    64
#define C_    256
#define NH_   8
#define N_    16
#define PIX_  (B_*H_*W_)     // 131072
#define OUTPIX_ (B_*32*32)   // 32768

typedef __hip_bfloat16 bf16;
typedef __attribute__((ext_vector_type(8))) short bf16x8;   // 8 bf16 = 4 VGPR
typedef __attribute__((ext_vector_type(4))) float f32x4;

__device__ __forceinline__ float bf2f(unsigned short u) {
  union { unsigned int i; float f; } v; v.i = ((unsigned int)u) << 16; return v.f;
}
__device__ __forceinline__ unsigned pk2(float a, float b) {
  union { __hip_bfloat162 h2; unsigned u; } c;
  c.h2 = __float22bfloat162_rn(make_float2(a, b));
  return c.u;
}

// ---------------------------------------------------------------------------
// K1: s0[8][16] (softmax row 0 of logits) and qv[8]. One block.
// ---------------------------------------------------------------------------
__global__ __launch_bounds__(256) void k1_setup(
    const float* __restrict__ emb, const float* __restrict__ wkq_w,
    const float* __restrict__ wkq_b, const float* __restrict__ wgq_w,
    const float* __restrict__ wgq_b,
    float* __restrict__ s0, float* __restrict__ qv) {
  __shared__ float lq[128];
  __shared__ float lk[16][8];
  int t = threadIdx.x;
  if (t < 128) {
    float acc = wkq_b[128 + t];
    for (int e = 0; e < 128; ++e) acc += emb[e] * wkq_w[e * 256 + 128 + t];
    lq[t] = acc;
  } else {
    int idx = t - 128; int j = idx >> 3, h = idx & 7;
    float acc = wkq_b[h * 16];
    for (int e = 0; e < 128; ++e) acc += emb[j * 128 + e] * wkq_w[e * 256 + h * 16];
    lk[j][h] = acc;
  }
  __syncthreads();
  if (t < 8) {
    float l[16]; float m = -1e30f;
    for (int j = 0; j < 16; ++j) { l[j] = lq[t * 16 + j] + lk[j][t]; m = fmaxf(m, l[j]); }
    float s = 0.f;
    for (int j = 0; j < 16; ++j) { l[j] = expf(l[j] - m); s += l[j]; }
    float inv = 1.f / s;
    for (int j = 0; j < 16; ++j) s0[t * 16 + j] = l[j] * inv;
    float acc = wgq_b[t];
    for (int e = 0; e < 128; ++e) acc += emb[14 * 128 + e] * wgq_w[e * 8 + t];
    qv[t] = acc;
  }
}

// ---------------------------------------------------------------------------
// prep: LDS-tiled transposes to bf16.
//   blocks 0..15 : wvT[n][k]  = wv[k][n]   (64x64 tiles)
//   blocks 16..31: wfT[n][k]  = wf[k][n]
//   block  32    : wgkT[a][k] = wgk[k][a]  (rows 8..15 zero)
// ---------------------------------------------------------------------------
__global__ __launch_bounds__(256) void prep(
    const float* __restrict__ wv, const float* __restrict__ wf,
    const float* __restrict__ wgk,
    bf16* __restrict__ wvT, bf16* __restrict__ wfT, bf16* __restrict__ wgkT) {
  int bid = blockIdx.x, t = threadIdx.x;
  if (bid < 32) {
    __shared__ unsigned short tile[64][72];
    const float* src = (bid < 16) ? wv : wf;
    bf16* dst = (bid < 16) ? wvT : wfT;
    int tb = bid & 15, tr = tb >> 2, tc = tb & 3;
#pragma unroll
    for (int it = 0; it < 16; ++it) {
      int idx = it * 256 + t, row = idx >> 6, col = idx & 63;
      bf16 h = __float2bfloat16(src[(tr * 64 + row) * 256 + tc * 64 + col]);
      tile[row][col] = *(unsigned short*)&h;
    }
    __syncthreads();
#pragma unroll
    for (int it = 0; it < 16; ++it) {
      int idx = it * 256 + t, row = idx >> 6, col = idx & 63;
      dst[(tc * 64 + row) * 256 + (tr * 64 + col)] = *(bf16*)&tile[col][row];
    }
  } else {
    __shared__ float g[2048];
#pragma unroll
    for (int it = 0; it < 8; ++it) g[it * 256 + t] = wgk[it * 256 + t];
    __syncthreads();
#pragma unroll
    for (int it = 0; it < 16; ++it) {
      int idx = it * 256 + t, a = idx >> 8, k = idx & 255;
      float v = (a < 8) ? g[k * 8 + a] : 0.f;
      wgkT[a * 256 + k] = __float2bfloat16(v);
    }
  }
}

// ---------------------------------------------------------------------------
// kA v5 (v1 skeleton + 2-phase half-K pipeline):
//   vraw = inps @ wv + wv_b          (bf16 out, no scale yet)
//   g    = relu(qv + inps @ wgk + b) -> gbuf; denom += sum(g)
// 2048 blocks x 1 tile of 64 px (the empirically-clean traffic regime).
// Within the tile, K=256 is split into two 128-col halves staged into a
// double LDS buffer: loads for half1 are issued BEFORE the barrier and stay
// in flight under half0's compute (compiler places the vmcnt wait at the
// half1 ds_write, which sits after compute0 in program order).
// Wave tile M32xN64 (8 waves). Gate rides nw==0 waves.
// ---------------------------------------------------------------------------
__global__ __launch_bounds__(512, 4) void kA(
    const float* __restrict__ inps, const bf16* __restrict__ wvT,
    const bf16* __restrict__ wgkT, const float* __restrict__ wv_b,
    const float* __restrict__ wgk_b, const float* __restrict__ qv,
    bf16* __restrict__ vraw, float* __restrict__ gbuf,
    float* __restrict__ denom) {
  // [2 halves][64 rows][128 bf16 + 8 pad] = 34816 B -> 4 blocks/CU LDS-wise
  __shared__ __align__(16) unsigned short ldsA[2][64][136];
  __shared__ float sden[8];
  __shared__ float qvb_s[8];
  int t = threadIdx.x;
  const long pix0 = (long)blockIdx.x * 64;
  if (t < 8) { sden[t] = 0.f; qvb_s[t] = qv[t] + wgk_b[t]; }

  int wave = t >> 6, lane = t & 63;
  int mw = wave >> 2, nw = wave & 3;
  int m0 = mw * 32, n0 = nw * 64;
  int lm = lane & 15, q = lane >> 4;
  bool gatew = (nw == 0);
  const bf16* brow = wvT + (n0 + lm) * 256;
  const bf16* grow = wgkT + lm * 256;

  // staging: thread t covers rows {sr, sr+16, sr+32, sr+48}, float4 column
  // sc4 within a 64x128 half (4 float4 = 16 floats per thread per half).
  int sr = t >> 5, sc4 = t & 31;
  const float* sbase = inps + pix0 * 256 + sr * 256 + sc4 * 4;
  float4 st[4];

#define LOADH(h_)                                                            \
  {                                                                          \
    const float* s_ = sbase + (h_)*128;                                      \
    _Pragma("unroll")                                                        \
    for (int it = 0; it < 4; ++it)                                           \
      st[it] = *(const float4*)(s_ + it * 16 * 256);                         \
  }
#define WRITEH(h_)                                                           \
  {                                                                          \
    _Pragma("unroll")                                                        \
    for (int it = 0; it < 4; ++it)                                           \
      *(uint2*)&ldsA[h_][it * 16 + sr][sc4 * 4] =                            \
          make_uint2(pk2(st[it].x, st[it].y), pk2(st[it].z, st[it].w));      \
  }

  LOADH(0);
  WRITEH(0);
  LOADH(1);              // stays in flight under half-0 compute
  __syncthreads();

  f32x4 acc[2][4], accg[2];
#pragma unroll
  for (int mf = 0; mf < 2; ++mf) {
    accg[mf] = (f32x4){0.f, 0.f, 0.f, 0.f};
#pragma unroll
    for (int nf = 0; nf < 4; ++nf) acc[mf][nf] = (f32x4){0.f, 0.f, 0.f, 0.f};
  }

#define COMPUTEH(h_)                                                         \
  {                                                                          \
    const unsigned short* arow0 = &ldsA[h_][m0 + lm][0];                     \
    const unsigned short* arow1 = &ldsA[h_][m0 + 16 + lm][0];                \
    _Pragma("unroll")                                                        \
    for (int ksl = 0; ksl < 4; ++ksl) {                                      \
      int kof = ksl * 32 + q * 8;                                            \
      bf16x8 a0 = *(const bf16x8*)(arow0 + kof);                             \
      bf16x8 a1 = *(const bf16x8*)(arow1 + kof);                             \
      int gk = (h_)*128 + kof;                                               \
      bf16x8 b0 = *(const bf16x8*)(brow + gk);                               \
      bf16x8 b1 = *(const bf16x8*)(brow + 4096 + gk);                        \
      bf16x8 b2 = *(const bf16x8*)(brow + 8192 + gk);                        \
      bf16x8 b3 = *(const bf16x8*)(brow + 12288 + gk);                       \
      acc[0][0] = __builtin_amdgcn_mfma_f32_16x16x32_bf16(a0, b0, acc[0][0], 0, 0, 0); \
      acc[1][0] = __builtin_amdgcn_mfma_f32_16x16x32_bf16(a1, b0, acc[1][0], 0, 0, 0); \
      acc[0][1] = __builtin_amdgcn_mfma_f32_16x16x32_bf16(a0, b1, acc[0][1], 0, 0, 0); \
      acc[1][1] = __builtin_amdgcn_mfma_f32_16x16x32_bf16(a1, b1, acc[1][1], 0, 0, 0); \
      acc[0][2] = __builtin_amdgcn_mfma_f32_16x16x32_bf16(a0, b2, acc[0][2], 0, 0, 0); \
      acc[1][2] = __builtin_amdgcn_mfma_f32_16x16x32_bf16(a1, b2, acc[1][2], 0, 0, 0); \
      acc[0][3] = __builtin_amdgcn_mfma_f32_16x16x32_bf16(a0, b3, acc[0][3], 0, 0, 0); \
      acc[1][3] = __builtin_amdgcn_mfma_f32_16x16x32_bf16(a1, b3, acc[1][3], 0, 0, 0); \
      if (gatew) {                                                           \
        bf16x8 bg = *(const bf16x8*)(grow + gk);                             \
        accg[0] = __builtin_amdgcn_mfma_f32_16x16x32_bf16(a0, bg, accg[0], 0, 0, 0); \
        accg[1] = __builtin_amdgcn_mfma_f32_16x16x32_bf16(a1, bg, accg[1], 0, 0, 0); \
      }                                                                      \
    }                                                                        \
  }

  COMPUTEH(0);           // half-1 global loads still outstanding here
  WRITEH(1);             // vmcnt wait lands here, after compute-0
  __syncthreads();
  COMPUTEH(1);

  // vraw epilogue (bias only; scale applied in kB)
#pragma unroll
  for (int nf = 0; nf < 4; ++nf) {
    int col = n0 + nf * 16 + lm;
    float wb = wv_b[col];
#pragma unroll
    for (int mf = 0; mf < 2; ++mf) {
#pragma unroll
      for (int r = 0; r < 4; ++r) {
        int rl = m0 + mf * 16 + q * 4 + r;
        vraw[(pix0 + rl) * 256 + col] = __float2bfloat16(acc[mf][nf][r] + wb);
      }
    }
  }

  // gate epilogue
  if (gatew) {
    float part = 0.f;
    if (lm < 8) {
#pragma unroll
      for (int mf = 0; mf < 2; ++mf) {
#pragma unroll
        for (int r = 0; r < 4; ++r) {
          int rl = m0 + mf * 16 + q * 4 + r;
          float gg = fmaxf(qvb_s[lm] + accg[mf][r], 0.f);
          gbuf[(pix0 + rl) * 8 + lm] = gg;
          part += gg;
        }
      }
    }
    part += __shfl_xor(part, 16, 64);
    part += __shfl_xor(part, 32, 64);
    if (lane < 16 && lm < 8) atomicAdd(&sden[lm], part);
  }
  __syncthreads();
  if (t < 8) atomicAdd(&denom[(int)(pix0 >> 12) * 8 + t], sden[t]);
#undef LOADH
#undef WRITEH
#undef COMPUTEH
}

// ---------------------------------------------------------------------------
// kB (fused scale + patch gather + final GEMM). Block = (b,x) row, 256 thr.
// Phase 0: stage scf[i][c][a] = 4096/(denom+eps)*g for the 4 source rows.
// Phase 1: op[y][ch] = sum_taps (s0*scf) * vraw   (uint = 2ch per lane)
// Phase 2: out = op @ wf + wf_b via MFMA (wfT in L2).
// ---------------------------------------------------------------------------
__global__ __launch_bounds__(256) void kB(
    const bf16* __restrict__ vraw, const float* __restrict__ s0,
    const float* __restrict__ gbuf, const float* __restrict__ denom,
    const bf16* __restrict__ wfT, const float* __restrict__ wf_b,
    float* __restrict__ out) {
  __shared__ float scfsh[4][64][8];                      // 8 KB
  __shared__ __align__(16) unsigned short opsh[32][264]; // bf16 bits
  int t = threadIdx.x;
  int bx = blockIdx.x, b = bx >> 5, x = bx & 31;

  { // phase 0
    int i = t >> 6, c = t & 63;
    int r = 2 * x + i - 1;
    if (r >= 0 && r < 64) {
      long p = (long)b * 4096 + r * 64 + c;
#pragma unroll
      for (int a = 0; a < 8; ++a)
        scfsh[i][c][a] = 4096.0f / (denom[b * 8 + a] + 1e-6f) * gbuf[p * 8 + a];
    } else {
#pragma unroll
      for (int a = 0; a < 8; ++a) scfsh[i][c][a] = 0.f;
    }
  }
  __syncthreads();

  // phase 1
  int c2 = t & 127, yg = t >> 7;
  int h = c2 >> 4;
  float s0r[16];
#pragma unroll
  for (int n = 0; n < 16; ++n) s0r[n] = s0[h * 16 + n];
  const bf16* vsb = vraw + (long)b * (4096 * 256);
  for (int yi = 0; yi < 16; ++yi) {
    int y = yi * 2 + yg;
    float p0 = 0.f, p1 = 0.f;
#pragma unroll
    for (int i = 0; i < 4; ++i) {
      int r = 2 * x + i - 1;
      if (r < 0 || r >= 64) continue;               // block-uniform
      const bf16* rowp = vsb + (long)r * 64 * 256 + 2 * c2;
#pragma unroll
      for (int j = 0; j < 4; ++j) {
        int c = 2 * y + j - 1;
        if (c < 0 || c >= 64) continue;             // wave-uniform
        float coef = s0r[i * 4 + j] * scfsh[i][c][h];
        unsigned u = *(const unsigned*)(rowp + (long)c * 256);
        p0 += coef * bf2f((unsigned short)(u & 0xffff));
        p1 += coef * bf2f((unsigned short)(u >> 16));
      }
    }
    *(unsigned*)&opsh[y][2 * c2] = pk2(p0, p1);
  }
  __syncthreads();

  // phase 2: MFMA  out[32x256] = op @ wf + b
  int wave = t >> 6, lane = t & 63;
  int n0 = wave * 64;
  int lm = lane & 15, q = lane >> 4;
  f32x4 acc[2][4];
#pragma unroll
  for (int mf = 0; mf < 2; ++mf)
#pragma unroll
    for (int nf = 0; nf < 4; ++nf) acc[mf][nf] = (f32x4){0.f, 0.f, 0.f, 0.f};
  const bf16* brow = wfT + (n0 + lm) * 256;
#pragma unroll
  for (int ks = 0; ks < 8; ++ks) {
    int kof = ks * 32 + q * 8;
    bf16x8 a0 = *(const bf16x8*)(&opsh[lm][kof]);
    bf16x8 a1 = *(const bf16x8*)(&opsh[16 + lm][kof]);
#pragma unroll
    for (int nf = 0; nf < 4; ++nf) {
      bf16x8 bb = *(const bf16x8*)(brow + nf * 4096 + kof);
      acc[0][nf] = __builtin_amdgcn_mfma_f32_16x16x32_bf16(a0, bb, acc[0][nf], 0, 0, 0);
      acc[1][nf] = __builtin_amdgcn_mfma_f32_16x16x32_bf16(a1, bb, acc[1][nf], 0, 0, 0);
    }
  }
  long out0 = (long)bx * 32 * 256;
#pragma unroll
  for (int nf = 0; nf < 4; ++nf) {
    int col = n0 + nf * 16 + lm;
    float wb = wf_b[col];
#pragma unroll
    for (int mf = 0; mf < 2; ++mf) {
#pragma unroll
      for (int r = 0; r < 4; ++r) {
        int row = mf * 16 + q * 4 + r;
        out[out0 + row * 256 + col] = acc[mf][nf][r] + wb;
      }
    }
  }
}

// ---------------------------------------------------------------------------
// Workspace (float offsets): s0 0 | qv 128 | denom 256 | gbuf 1024 (+1M)
// wvT @1049600 (+32768) | wfT @1082368 (+32768) | wgkT @1115136 (+2048)
// vraw(bf16) @1117184 (+16.7M f-equiv). Total ~71.6 MB.
// ---------------------------------------------------------------------------
extern "C" void kernel_launch(void* const* d_in, const int* in_sizes, int n_in,
                              void* d_out, int out_size, void* d_ws, size_t ws_size,
                              hipStream_t stream) {
  const float* inps  = (const float*)d_in[0];
  const float* emb   = (const float*)d_in[1];
  const float* wkq_w = (const float*)d_in[2];
  const float* wkq_b = (const float*)d_in[3];
  const float* wv_w  = (const float*)d_in[4];
  const float* wv_b  = (const float*)d_in[5];
  const float* wgq_w = (const float*)d_in[6];
  const float* wgq_b = (const float*)d_in[7];
  const float* wgk_w = (const float*)d_in[8];
  const float* wgk_b = (const float*)d_in[9];
  const float* wf_w  = (const float*)d_in[10];
  const float* wf_b  = (const float*)d_in[11];

  float* wsf   = (float*)d_ws;
  float* s0f   = wsf;
  float* qvf   = wsf + 128;
  float* denom = wsf + 256;
  float* gbuf  = wsf + 1024;
  bf16*  wvT   = (bf16*)(wsf + 1049600);
  bf16*  wfT   = (bf16*)(wsf + 1082368);
  bf16*  wgkT  = (bf16*)(wsf + 1115136);
  bf16*  vraw  = (bf16*)(wsf + 1117184);
  float* outp  = (float*)d_out;

  hipMemsetAsync((void*)denom, 0, 1024, stream);
  k1_setup<<<1, 256, 0, stream>>>(emb, wkq_w, wkq_b, wgq_w, wgq_b, s0f, qvf);
  prep<<<33, 256, 0, stream>>>(wv_w, wf_w, wgk_w, wvT, wfT, wgkT);
  kA<<<PIX_ / 64, 512, 0, stream>>>(inps, wvT, wgkT, wv_b, wgk_b, qvf,
                                    vraw, gbuf, denom);
  kB<<<OUTPIX_ / 32, 256, 0, stream>>>(vraw, s0f, gbuf, denom, wfT, wf_b, outp);
}

// Round 5
// 339.496 us; speedup vs baseline: 1.2292x; 1.1216x over previous
//
#include <hip/hip_runtime.h>
#include <hip/hip_bf16.h>

// Problem constants
#define B_    32
#define H_    64
#define W_    64
#define C_    256
#define NH_   8
#define N_    16
#define PIX_  (B_*H_*W_)     // 131072
#define OUTPIX_ (B_*32*32)   // 32768

typedef __hip_bfloat16 bf16;
typedef __attribute__((ext_vector_type(8))) short bf16x8;   // 8 bf16 = 4 VGPR
typedef __attribute__((ext_vector_type(4))) float f32x4;

__device__ __forceinline__ float bf2f(unsigned short u) {
  union { unsigned int i; float f; } v; v.i = ((unsigned int)u) << 16; return v.f;
}
__device__ __forceinline__ unsigned pk2(float a, float b) {
  union { __hip_bfloat162 h2; unsigned u; } c;
  c.h2 = __float22bfloat162_rn(make_float2(a, b));
  return c.u;
}

// ---------------------------------------------------------------------------
// K1: s0[8][16] (softmax row 0 of logits) and qv[8]. One block.
// ---------------------------------------------------------------------------
__global__ __launch_bounds__(256) void k1_setup(
    const float* __restrict__ emb, const float* __restrict__ wkq_w,
    const float* __restrict__ wkq_b, const float* __restrict__ wgq_w,
    const float* __restrict__ wgq_b,
    float* __restrict__ s0, float* __restrict__ qv) {
  __shared__ float lq[128];
  __shared__ float lk[16][8];
  int t = threadIdx.x;
  if (t < 128) {
    float acc = wkq_b[128 + t];
    for (int e = 0; e < 128; ++e) acc += emb[e] * wkq_w[e * 256 + 128 + t];
    lq[t] = acc;
  } else {
    int idx = t - 128; int j = idx >> 3, h = idx & 7;
    float acc = wkq_b[h * 16];
    for (int e = 0; e < 128; ++e) acc += emb[j * 128 + e] * wkq_w[e * 256 + h * 16];
    lk[j][h] = acc;
  }
  __syncthreads();
  if (t < 8) {
    float l[16]; float m = -1e30f;
    for (int j = 0; j < 16; ++j) { l[j] = lq[t * 16 + j] + lk[j][t]; m = fmaxf(m, l[j]); }
    float s = 0.f;
    for (int j = 0; j < 16; ++j) { l[j] = expf(l[j] - m); s += l[j]; }
    float inv = 1.f / s;
    for (int j = 0; j < 16; ++j) s0[t * 16 + j] = l[j] * inv;
    float acc = wgq_b[t];
    for (int e = 0; e < 128; ++e) acc += emb[14 * 128 + e] * wgq_w[e * 8 + t];
    qv[t] = acc;
  }
}

// ---------------------------------------------------------------------------
// prep: LDS-tiled transposes to bf16.
//   blocks 0..15 : wvT[n][k]  = wv[k][n]   (64x64 tiles)
//   blocks 16..31: wfT[n][k]  = wf[k][n]
//   block  32    : wgkT[a][k] = wgk[k][a]  (rows 8..15 zero)
// ---------------------------------------------------------------------------
__global__ __launch_bounds__(256) void prep(
    const float* __restrict__ wv, const float* __restrict__ wf,
    const float* __restrict__ wgk,
    bf16* __restrict__ wvT, bf16* __restrict__ wfT, bf16* __restrict__ wgkT) {
  int bid = blockIdx.x, t = threadIdx.x;
  if (bid < 32) {
    __shared__ unsigned short tile[64][72];
    const float* src = (bid < 16) ? wv : wf;
    bf16* dst = (bid < 16) ? wvT : wfT;
    int tb = bid & 15, tr = tb >> 2, tc = tb & 3;
#pragma unroll
    for (int it = 0; it < 16; ++it) {
      int idx = it * 256 + t, row = idx >> 6, col = idx & 63;
      bf16 h = __float2bfloat16(src[(tr * 64 + row) * 256 + tc * 64 + col]);
      tile[row][col] = *(unsigned short*)&h;
    }
    __syncthreads();
#pragma unroll
    for (int it = 0; it < 16; ++it) {
      int idx = it * 256 + t, row = idx >> 6, col = idx & 63;
      dst[(tc * 64 + row) * 256 + (tr * 64 + col)] = *(bf16*)&tile[col][row];
    }
  } else {
    __shared__ float g[2048];
#pragma unroll
    for (int it = 0; it < 8; ++it) g[it * 256 + t] = wgk[it * 256 + t];
    __syncthreads();
#pragma unroll
    for (int it = 0; it < 16; ++it) {
      int idx = it * 256 + t, a = idx >> 8, k = idx & 255;
      float v = (a < 8) ? g[k * 8 + a] : 0.f;
      wgkT[a * 256 + k] = __float2bfloat16(v);
    }
  }
}

// ---------------------------------------------------------------------------
// kA v6 (batch-load-then-burst):
//   vraw = inps @ wv + wv_b          (bf16 out, no scale yet)
//   g    = relu(qv + inps @ wgk + b) -> gbuf; denom += sum(g)
// 2048 blocks x 64 px (clean-traffic regime). Single-shot staging (v1),
// one barrier. K-loop restructured into 4 sub-batches: issue ALL operand
// loads (8 global B + 2 gate-B + 4 LDS A) back-to-back, one wait, then a
// 16-20 MFMA burst -> ~10 loads in flight per wave instead of 1.
// Wave tile M32xN64 (8 waves). Gate rides nw==0 waves.
// ---------------------------------------------------------------------------
__global__ __launch_bounds__(512, 4) void kA(
    const float* __restrict__ inps, const bf16* __restrict__ wvT,
    const bf16* __restrict__ wgkT, const float* __restrict__ wv_b,
    const float* __restrict__ wgk_b, const float* __restrict__ qv,
    bf16* __restrict__ vraw, float* __restrict__ gbuf,
    float* __restrict__ denom) {
  // [2 K-halves][64 rows][128 bf16 + 8 pad] = 34816 B
  __shared__ __align__(16) unsigned short ldsA[2][64][136];
  __shared__ float sden[8];
  __shared__ float qvb_s[8];
  int t = threadIdx.x;
  const long pix0 = (long)blockIdx.x * 64;
  if (t < 8) { sden[t] = 0.f; qvb_s[t] = qv[t] + wgk_b[t]; }

  // single-shot staging: 64x256 fp32 -> bf16 LDS (8 independent float4/thr)
  const float* src = inps + pix0 * 256;
#pragma unroll
  for (int it = 0; it < 8; ++it) {
    int idx = it * 512 + t;
    int row = idx >> 6, c4 = (idx & 63) << 2;   // c4: float col 0..252
    float4 v = *(const float4*)(src + row * 256 + c4);
    *(uint2*)&ldsA[c4 >> 7][row][c4 & 127] =
        make_uint2(pk2(v.x, v.y), pk2(v.z, v.w));
  }
  __syncthreads();

  int wave = t >> 6, lane = t & 63;
  int mw = wave >> 2, nw = wave & 3;
  int m0 = mw * 32, n0 = nw * 64;
  int lm = lane & 15, q = lane >> 4;
  bool gatew = (nw == 0);
  const bf16* brow = wvT + (n0 + lm) * 256;
  const bf16* grow = wgkT + lm * 256;

  f32x4 acc[2][4], accg[2];
#pragma unroll
  for (int mf = 0; mf < 2; ++mf) {
    accg[mf] = (f32x4){0.f, 0.f, 0.f, 0.f};
#pragma unroll
    for (int nf = 0; nf < 4; ++nf) acc[mf][nf] = (f32x4){0.f, 0.f, 0.f, 0.f};
  }

  // 4 sub-batches x 2 K-steps: load cluster -> wait -> MFMA burst
#pragma unroll
  for (int sb = 0; sb < 4; ++sb) {
    bf16x8 A0[2], A1[2], Bv[2][4], Bg[2];
#pragma unroll
    for (int k2 = 0; k2 < 2; ++k2) {
      int ks = sb * 2 + k2;                 // global K-step 0..7
      int h = ks >> 2;
      int kof = (ks & 3) * 32 + q * 8;      // bf16 col within half
      int gk = ks * 32 + q * 8;             // bf16 col within full K
#pragma unroll
      for (int nf = 0; nf < 4; ++nf)
        Bv[k2][nf] = *(const bf16x8*)(brow + nf * 4096 + gk);
      if (gatew) Bg[k2] = *(const bf16x8*)(grow + gk);
      A0[k2] = *(const bf16x8*)(&ldsA[h][m0 + lm][kof]);
      A1[k2] = *(const bf16x8*)(&ldsA[h][m0 + 16 + lm][kof]);
    }
#pragma unroll
    for (int k2 = 0; k2 < 2; ++k2) {
#pragma unroll
      for (int nf = 0; nf < 4; ++nf) {
        acc[0][nf] = __builtin_amdgcn_mfma_f32_16x16x32_bf16(A0[k2], Bv[k2][nf], acc[0][nf], 0, 0, 0);
        acc[1][nf] = __builtin_amdgcn_mfma_f32_16x16x32_bf16(A1[k2], Bv[k2][nf], acc[1][nf], 0, 0, 0);
      }
      if (gatew) {
        accg[0] = __builtin_amdgcn_mfma_f32_16x16x32_bf16(A0[k2], Bg[k2], accg[0], 0, 0, 0);
        accg[1] = __builtin_amdgcn_mfma_f32_16x16x32_bf16(A1[k2], Bg[k2], accg[1], 0, 0, 0);
      }
    }
  }

  // vraw epilogue (bias only; scale applied in kB)
#pragma unroll
  for (int nf = 0; nf < 4; ++nf) {
    int col = n0 + nf * 16 + lm;
    float wb = wv_b[col];
#pragma unroll
    for (int mf = 0; mf < 2; ++mf) {
#pragma unroll
      for (int r = 0; r < 4; ++r) {
        int rl = m0 + mf * 16 + q * 4 + r;
        vraw[(pix0 + rl) * 256 + col] = __float2bfloat16(acc[mf][nf][r] + wb);
      }
    }
  }

  // gate epilogue
  if (gatew) {
    float part = 0.f;
    if (lm < 8) {
#pragma unroll
      for (int mf = 0; mf < 2; ++mf) {
#pragma unroll
        for (int r = 0; r < 4; ++r) {
          int rl = m0 + mf * 16 + q * 4 + r;
          float gg = fmaxf(qvb_s[lm] + accg[mf][r], 0.f);
          gbuf[(pix0 + rl) * 8 + lm] = gg;
          part += gg;
        }
      }
    }
    part += __shfl_xor(part, 16, 64);
    part += __shfl_xor(part, 32, 64);
    if (lane < 16 && lm < 8) atomicAdd(&sden[lm], part);
  }
  __syncthreads();
  if (t < 8) atomicAdd(&denom[(int)(pix0 >> 12) * 8 + t], sden[t]);
}

// ---------------------------------------------------------------------------
// kB v6 (fused scale + patch gather + final GEMM). Block = (b,x) row, 256 thr.
// Phase 0: stage scf[i][c][a] = 4096/(denom+eps)*g (float4 gbuf reads).
// Phase 1: op[y][ch] = sum_taps (s0*scf) * vraw, with double-buffered
//          prefetch of the 16 scattered vraw taps (next-y loads issued
//          before current-y FMA chain; clamped addresses, scfsh-zero picks
//          up OOB rows, explicit predicate zeroes OOB cols).
// Phase 2: out = op @ wf + wf_b via MFMA (wfT in L2).
// ---------------------------------------------------------------------------
__global__ __launch_bounds__(256) void kB(
    const bf16* __restrict__ vraw, const float* __restrict__ s0,
    const float* __restrict__ gbuf, const float* __restrict__ denom,
    const bf16* __restrict__ wfT, const float* __restrict__ wf_b,
    float* __restrict__ out) {
  __shared__ float scfsh[4][64][8];                      // 8 KB
  __shared__ __align__(16) unsigned short opsh[32][264]; // bf16 bits
  int t = threadIdx.x;
  int bx = blockIdx.x, b = bx >> 5, x = bx & 31;

  { // phase 0
    int i = t >> 6, c = t & 63;
    int r = 2 * x + i - 1;
    if (r >= 0 && r < 64) {
      float dn[8];
#pragma unroll
      for (int a = 0; a < 8; ++a) dn[a] = 4096.0f / (denom[b * 8 + a] + 1e-6f);
      long p = (long)b * 4096 + r * 64 + c;
      const float4* gp = (const float4*)&gbuf[p * 8];
      float4 g0 = gp[0], g1 = gp[1];
      scfsh[i][c][0] = dn[0] * g0.x;
      scfsh[i][c][1] = dn[1] * g0.y;
      scfsh[i][c][2] = dn[2] * g0.z;
      scfsh[i][c][3] = dn[3] * g0.w;
      scfsh[i][c][4] = dn[4] * g1.x;
      scfsh[i][c][5] = dn[5] * g1.y;
      scfsh[i][c][6] = dn[6] * g1.z;
      scfsh[i][c][7] = dn[7] * g1.w;
    } else {
#pragma unroll
      for (int a = 0; a < 8; ++a) scfsh[i][c][a] = 0.f;
    }
  }
  __syncthreads();

  // phase 1
  int c2 = t & 127, yg = t >> 7;
  int h = c2 >> 4;
  float s0r[16];
#pragma unroll
  for (int n = 0; n < 16; ++n) s0r[n] = s0[h * 16 + n];
  const bf16* vsb = vraw + (long)b * (4096 * 256);
  const bf16* rp[4];
#pragma unroll
  for (int i = 0; i < 4; ++i) {
    int r = 2 * x + i - 1;
    int rc = min(max(r, 0), 63);            // clamp addr; scfsh==0 kills coef
    rp[i] = vsb + (long)rc * 64 * 256 + 2 * c2;
  }

#define LOADYI(U, y_)                                                        \
  {                                                                          \
    _Pragma("unroll") for (int i_ = 0; i_ < 4; ++i_) {                       \
      _Pragma("unroll") for (int j_ = 0; j_ < 4; ++j_) {                     \
        int c_ = 2 * (y_) + j_ - 1;                                          \
        int cc_ = min(max(c_, 0), 63);                                       \
        U[i_][j_] = *(const unsigned*)(rp[i_] + (long)cc_ * 256);            \
      }                                                                      \
    }                                                                        \
  }
#define COMPYI(U, y_)                                                        \
  {                                                                          \
    float p0 = 0.f, p1 = 0.f;                                                \
    _Pragma("unroll") for (int i_ = 0; i_ < 4; ++i_) {                       \
      _Pragma("unroll") for (int j_ = 0; j_ < 4; ++j_) {                     \
        int c_ = 2 * (y_) + j_ - 1;                                          \
        float coef = (c_ >= 0 && c_ < 64)                                    \
                         ? s0r[i_ * 4 + j_] * scfsh[i_][c_][h]               \
                         : 0.f;                                              \
        unsigned u_ = U[i_][j_];                                             \
        p0 += coef * bf2f((unsigned short)(u_ & 0xffff));                    \
        p1 += coef * bf2f((unsigned short)(u_ >> 16));                       \
      }                                                                      \
    }                                                                        \
    *(unsigned*)&opsh[y_][2 * c2] = pk2(p0, p1);                             \
  }

  {
    unsigned UA[4][4], UB[4][4];
    LOADYI(UA, yg);                        // yi=0 -> y = yg
#pragma unroll
    for (int yp = 0; yp < 8; ++yp) {
      int yA = (2 * yp) * 2 + yg;
      int yB = (2 * yp + 1) * 2 + yg;
      LOADYI(UB, yB);                      // in flight during A's FMA chain
      COMPYI(UA, yA);
      if (yp < 7) {
        int yA2 = (2 * yp + 2) * 2 + yg;
        LOADYI(UA, yA2);                   // in flight during B's FMA chain
      }
      COMPYI(UB, yB);
    }
  }
#undef LOADYI
#undef COMPYI
  __syncthreads();

  // phase 2: MFMA  out[32x256] = op @ wf + b
  int wave = t >> 6, lane = t & 63;
  int n0 = wave * 64;
  int lm = lane & 15, q = lane >> 4;
  f32x4 acc[2][4];
#pragma unroll
  for (int mf = 0; mf < 2; ++mf)
#pragma unroll
    for (int nf = 0; nf < 4; ++nf) acc[mf][nf] = (f32x4){0.f, 0.f, 0.f, 0.f};
  const bf16* brow = wfT + (n0 + lm) * 256;
#pragma unroll
  for (int ks = 0; ks < 8; ++ks) {
    int kof = ks * 32 + q * 8;
    bf16x8 a0 = *(const bf16x8*)(&opsh[lm][kof]);
    bf16x8 a1 = *(const bf16x8*)(&opsh[16 + lm][kof]);
#pragma unroll
    for (int nf = 0; nf < 4; ++nf) {
      bf16x8 bb = *(const bf16x8*)(brow + nf * 4096 + kof);
      acc[0][nf] = __builtin_amdgcn_mfma_f32_16x16x32_bf16(a0, bb, acc[0][nf], 0, 0, 0);
      acc[1][nf] = __builtin_amdgcn_mfma_f32_16x16x32_bf16(a1, bb, acc[1][nf], 0, 0, 0);
    }
  }
  long out0 = (long)bx * 32 * 256;
#pragma unroll
  for (int nf = 0; nf < 4; ++nf) {
    int col = n0 + nf * 16 + lm;
    float wb = wf_b[col];
#pragma unroll
    for (int mf = 0; mf < 2; ++mf) {
#pragma unroll
      for (int r = 0; r < 4; ++r) {
        int row = mf * 16 + q * 4 + r;
        out[out0 + row * 256 + col] = acc[mf][nf][r] + wb;
      }
    }
  }
}

// ---------------------------------------------------------------------------
// Workspace (float offsets): s0 0 | qv 128 | denom 256 | gbuf 1024 (+1M)
// wvT @1049600 (+32768) | wfT @1082368 (+32768) | wgkT @1115136 (+2048)
// vraw(bf16) @1117184 (+16.7M f-equiv). Total ~71.6 MB.
// ---------------------------------------------------------------------------
extern "C" void kernel_launch(void* const* d_in, const int* in_sizes, int n_in,
                              void* d_out, int out_size, void* d_ws, size_t ws_size,
                              hipStream_t stream) {
  const float* inps  = (const float*)d_in[0];
  const float* emb   = (const float*)d_in[1];
  const float* wkq_w = (const float*)d_in[2];
  const float* wkq_b = (const float*)d_in[3];
  const float* wv_w  = (const float*)d_in[4];
  const float* wv_b  = (const float*)d_in[5];
  const float* wgq_w = (const float*)d_in[6];
  const float* wgq_b = (const float*)d_in[7];
  const float* wgk_w = (const float*)d_in[8];
  const float* wgk_b = (const float*)d_in[9];
  const float* wf_w  = (const float*)d_in[10];
  const float* wf_b  = (const float*)d_in[11];

  float* wsf   = (float*)d_ws;
  float* s0f   = wsf;
  float* qvf   = wsf + 128;
  float* denom = wsf + 256;
  float* gbuf  = wsf + 1024;
  bf16*  wvT   = (bf16*)(wsf + 1049600);
  bf16*  wfT   = (bf16*)(wsf + 1082368);
  bf16*  wgkT  = (bf16*)(wsf + 1115136);
  bf16*  vraw  = (bf16*)(wsf + 1117184);
  float* outp  = (float*)d_out;

  hipMemsetAsync((void*)denom, 0, 1024, stream);
  k1_setup<<<1, 256, 0, stream>>>(emb, wkq_w, wkq_b, wgq_w, wgq_b, s0f, qvf);
  prep<<<33, 256, 0, stream>>>(wv_w, wf_w, wgk_w, wvT, wfT, wgkT);
  kA<<<PIX_ / 64, 512, 0, stream>>>(inps, wvT, wgkT, wv_b, wgk_b, qvf,
                                    vraw, gbuf, denom);
  kB<<<OUTPIX_ / 32, 256, 0, stream>>>(vraw, s0f, gbuf, denom, wfT, wf_b, outp);
}

// Round 6
// 338.942 us; speedup vs baseline: 1.2312x; 1.0016x over previous
//
#include <hip/hip_runtime.h>
#include <hip/hip_bf16.h>

// Problem constants
#define B_    32
#define H_    64
#define W_    64
#define C_    256
#define NH_   8
#define N_    16
#define PIX_  (B_*H_*W_)     // 131072
#define OUTPIX_ (B_*32*32)   // 32768

typedef __hip_bfloat16 bf16;
typedef __attribute__((ext_vector_type(8))) short bf16x8;   // 8 bf16 = 4 VGPR
typedef __attribute__((ext_vector_type(4))) float f32x4;

__device__ __forceinline__ float bf2f(unsigned short u) {
  union { unsigned int i; float f; } v; v.i = ((unsigned int)u) << 16; return v.f;
}
__device__ __forceinline__ unsigned pk2(float a, float b) {
  union { __hip_bfloat162 h2; unsigned u; } c;
  c.h2 = __float22bfloat162_rn(make_float2(a, b));
  return c.u;
}

// ---------------------------------------------------------------------------
// K1: s0[8][16] (softmax row 0 of logits) and qv[8]. One block.
// ---------------------------------------------------------------------------
__global__ __launch_bounds__(256) void k1_setup(
    const float* __restrict__ emb, const float* __restrict__ wkq_w,
    const float* __restrict__ wkq_b, const float* __restrict__ wgq_w,
    const float* __restrict__ wgq_b,
    float* __restrict__ s0, float* __restrict__ qv) {
  __shared__ float lq[128];
  __shared__ float lk[16][8];
  int t = threadIdx.x;
  if (t < 128) {
    float acc = wkq_b[128 + t];
    for (int e = 0; e < 128; ++e) acc += emb[e] * wkq_w[e * 256 + 128 + t];
    lq[t] = acc;
  } else {
    int idx = t - 128; int j = idx >> 3, h = idx & 7;
    float acc = wkq_b[h * 16];
    for (int e = 0; e < 128; ++e) acc += emb[j * 128 + e] * wkq_w[e * 256 + h * 16];
    lk[j][h] = acc;
  }
  __syncthreads();
  if (t < 8) {
    float l[16]; float m = -1e30f;
    for (int j = 0; j < 16; ++j) { l[j] = lq[t * 16 + j] + lk[j][t]; m = fmaxf(m, l[j]); }
    float s = 0.f;
    for (int j = 0; j < 16; ++j) { l[j] = expf(l[j] - m); s += l[j]; }
    float inv = 1.f / s;
    for (int j = 0; j < 16; ++j) s0[t * 16 + j] = l[j] * inv;
    float acc = wgq_b[t];
    for (int e = 0; e < 128; ++e) acc += emb[14 * 128 + e] * wgq_w[e * 8 + t];
    qv[t] = acc;
  }
}

// ---------------------------------------------------------------------------
// prep: LDS-tiled transposes to bf16.
//   blocks 0..15 : wvT[n][k]  = wv[k][n]   (64x64 tiles)
//   blocks 16..31: wfT[n][k]  = wf[k][n]
//   block  32    : wgkT[a][k] = wgk[k][a]  (rows 8..15 zero)
// ---------------------------------------------------------------------------
__global__ __launch_bounds__(256) void prep(
    const float* __restrict__ wv, const float* __restrict__ wf,
    const float* __restrict__ wgk,
    bf16* __restrict__ wvT, bf16* __restrict__ wfT, bf16* __restrict__ wgkT) {
  int bid = blockIdx.x, t = threadIdx.x;
  if (bid < 32) {
    __shared__ unsigned short tile[64][72];
    const float* src = (bid < 16) ? wv : wf;
    bf16* dst = (bid < 16) ? wvT : wfT;
    int tb = bid & 15, tr = tb >> 2, tc = tb & 3;
#pragma unroll
    for (int it = 0; it < 16; ++it) {
      int idx = it * 256 + t, row = idx >> 6, col = idx & 63;
      bf16 h = __float2bfloat16(src[(tr * 64 + row) * 256 + tc * 64 + col]);
      tile[row][col] = *(unsigned short*)&h;
    }
    __syncthreads();
#pragma unroll
    for (int it = 0; it < 16; ++it) {
      int idx = it * 256 + t, row = idx >> 6, col = idx & 63;
      dst[(tc * 64 + row) * 256 + (tr * 64 + col)] = *(bf16*)&tile[col][row];
    }
  } else {
    __shared__ float g[2048];
#pragma unroll
    for (int it = 0; it < 8; ++it) g[it * 256 + t] = wgk[it * 256 + t];
    __syncthreads();
#pragma unroll
    for (int it = 0; it < 16; ++it) {
      int idx = it * 256 + t, a = idx >> 8, k = idx & 255;
      float v = (a < 8) ? g[k * 8 + a] : 0.f;
      wgkT[a * 256 + k] = __float2bfloat16(v);
    }
  }
}

// ---------------------------------------------------------------------------
// kA v7 (pinned batch-burst + higher TLP):
//   vraw = inps @ wv + wv_b          (bf16 out, no scale yet)
//   g    = relu(qv + inps @ wgk + b) -> gbuf; denom += sum(g)
// 4096 blocks x 32 px, 256 threads (4 waves: nw=0..3, M32xN64 each).
// sched_barrier(0) fences pin {load cluster}->{MFMA burst} per sub-batch so
// the register allocator cannot re-serialize the loads (v6 failure mode:
// VGPR_Count=56 showed the batch was compiled away). Consecutive regions let
// sub-batch sb+1's loads co-issue into sb's burst. Staging loads likewise
// pinned 8-deep before the cvt+ds_write pass.
// ---------------------------------------------------------------------------
__global__ __launch_bounds__(256, 4) void kA(
    const float* __restrict__ inps, const bf16* __restrict__ wvT,
    const bf16* __restrict__ wgkT, const float* __restrict__ wv_b,
    const float* __restrict__ wgk_b, const float* __restrict__ qv,
    bf16* __restrict__ vraw, float* __restrict__ gbuf,
    float* __restrict__ denom) {
  // [2 K-halves][32 rows][128 bf16 + 8 pad] = 17408 B
  __shared__ __align__(16) unsigned short ldsA[2][32][136];
  __shared__ float sden[8];
  __shared__ float qvb_s[8];
  int t = threadIdx.x;
  const long pix0 = (long)blockIdx.x * 32;
  if (t < 8) { sden[t] = 0.f; qvb_s[t] = qv[t] + wgk_b[t]; }

  // staging: 32x256 fp32 -> bf16 LDS. 8 float4/thread, loads pinned first.
  {
    const float* src = inps + pix0 * 256;
    float4 st[8];
#pragma unroll
    for (int it = 0; it < 8; ++it) {
      int idx = it * 256 + t;
      int row = idx >> 6, c4 = (idx & 63) << 2;
      st[it] = *(const float4*)(src + row * 256 + c4);
    }
    __builtin_amdgcn_sched_barrier(0);   // all 8 loads issued before any use
#pragma unroll
    for (int it = 0; it < 8; ++it) {
      int idx = it * 256 + t;
      int row = idx >> 6, c4 = (idx & 63) << 2;
      *(uint2*)&ldsA[c4 >> 7][row][c4 & 127] =
          make_uint2(pk2(st[it].x, st[it].y), pk2(st[it].z, st[it].w));
    }
  }
  __syncthreads();

  int wave = t >> 6, lane = t & 63;
  int nw = wave;                    // 4 waves: one M32xN64 tile each
  int n0 = nw * 64;
  int lm = lane & 15, q = lane >> 4;
  bool gatew = (nw == 0);
  const bf16* brow = wvT + (n0 + lm) * 256;
  const bf16* grow = wgkT + lm * 256;

  f32x4 acc[2][4], accg[2];
#pragma unroll
  for (int mf = 0; mf < 2; ++mf) {
    accg[mf] = (f32x4){0.f, 0.f, 0.f, 0.f};
#pragma unroll
    for (int nf = 0; nf < 4; ++nf) acc[mf][nf] = (f32x4){0.f, 0.f, 0.f, 0.f};
  }

  // 4 sub-batches x 2 K-steps: {pinned load cluster} fence {MFMA burst}
#pragma unroll
  for (int sb = 0; sb < 4; ++sb) {
    bf16x8 A0[2], A1[2], Bv[2][4], Bg[2];
#pragma unroll
    for (int k2 = 0; k2 < 2; ++k2) {
      int ks = sb * 2 + k2;                 // global K-step 0..7
      int h = ks >> 2;
      int kof = (ks & 3) * 32 + q * 8;      // bf16 col within half
      int gk = ks * 32 + q * 8;             // bf16 col within full K
#pragma unroll
      for (int nf = 0; nf < 4; ++nf)
        Bv[k2][nf] = *(const bf16x8*)(brow + nf * 4096 + gk);
      if (gatew) Bg[k2] = *(const bf16x8*)(grow + gk);
      A0[k2] = *(const bf16x8*)(&ldsA[h][lm][kof]);
      A1[k2] = *(const bf16x8*)(&ldsA[h][16 + lm][kof]);
    }
    __builtin_amdgcn_sched_barrier(0);      // cluster may not sink past here
#pragma unroll
    for (int k2 = 0; k2 < 2; ++k2) {
#pragma unroll
      for (int nf = 0; nf < 4; ++nf) {
        acc[0][nf] = __builtin_amdgcn_mfma_f32_16x16x32_bf16(A0[k2], Bv[k2][nf], acc[0][nf], 0, 0, 0);
        acc[1][nf] = __builtin_amdgcn_mfma_f32_16x16x32_bf16(A1[k2], Bv[k2][nf], acc[1][nf], 0, 0, 0);
      }
      if (gatew) {
        accg[0] = __builtin_amdgcn_mfma_f32_16x16x32_bf16(A0[k2], Bg[k2], accg[0], 0, 0, 0);
        accg[1] = __builtin_amdgcn_mfma_f32_16x16x32_bf16(A1[k2], Bg[k2], accg[1], 0, 0, 0);
      }
    }
  }

  // vraw epilogue (bias only; scale applied in kB)
#pragma unroll
  for (int nf = 0; nf < 4; ++nf) {
    int col = n0 + nf * 16 + lm;
    float wb = wv_b[col];
#pragma unroll
    for (int mf = 0; mf < 2; ++mf) {
#pragma unroll
      for (int r = 0; r < 4; ++r) {
        int rl = mf * 16 + q * 4 + r;
        vraw[(pix0 + rl) * 256 + col] = __float2bfloat16(acc[mf][nf][r] + wb);
      }
    }
  }

  // gate epilogue
  if (gatew) {
    float part = 0.f;
    if (lm < 8) {
#pragma unroll
      for (int mf = 0; mf < 2; ++mf) {
#pragma unroll
        for (int r = 0; r < 4; ++r) {
          int rl = mf * 16 + q * 4 + r;
          float gg = fmaxf(qvb_s[lm] + accg[mf][r], 0.f);
          gbuf[(pix0 + rl) * 8 + lm] = gg;
          part += gg;
        }
      }
    }
    part += __shfl_xor(part, 16, 64);
    part += __shfl_xor(part, 32, 64);
    if (lane < 16 && lm < 8) atomicAdd(&sden[lm], part);
  }
  __syncthreads();
  if (t < 8) atomicAdd(&denom[(int)(blockIdx.x >> 7) * 8 + t], sden[t]);
}

// ---------------------------------------------------------------------------
// kB v6 (fused scale + patch gather + final GEMM). Block = (b,x) row, 256 thr.
// Phase 0: stage scf[i][c][a] = 4096/(denom+eps)*g (float4 gbuf reads).
// Phase 1: op[y][ch] = sum_taps (s0*scf) * vraw, double-buffered tap prefetch.
// Phase 2: out = op @ wf + wf_b via MFMA (wfT in L2).
// ---------------------------------------------------------------------------
__global__ __launch_bounds__(256) void kB(
    const bf16* __restrict__ vraw, const float* __restrict__ s0,
    const float* __restrict__ gbuf, const float* __restrict__ denom,
    const bf16* __restrict__ wfT, const float* __restrict__ wf_b,
    float* __restrict__ out) {
  __shared__ float scfsh[4][64][8];                      // 8 KB
  __shared__ __align__(16) unsigned short opsh[32][264]; // bf16 bits
  int t = threadIdx.x;
  int bx = blockIdx.x, b = bx >> 5, x = bx & 31;

  { // phase 0
    int i = t >> 6, c = t & 63;
    int r = 2 * x + i - 1;
    if (r >= 0 && r < 64) {
      float dn[8];
#pragma unroll
      for (int a = 0; a < 8; ++a) dn[a] = 4096.0f / (denom[b * 8 + a] + 1e-6f);
      long p = (long)b * 4096 + r * 64 + c;
      const float4* gp = (const float4*)&gbuf[p * 8];
      float4 g0 = gp[0], g1 = gp[1];
      scfsh[i][c][0] = dn[0] * g0.x;
      scfsh[i][c][1] = dn[1] * g0.y;
      scfsh[i][c][2] = dn[2] * g0.z;
      scfsh[i][c][3] = dn[3] * g0.w;
      scfsh[i][c][4] = dn[4] * g1.x;
      scfsh[i][c][5] = dn[5] * g1.y;
      scfsh[i][c][6] = dn[6] * g1.z;
      scfsh[i][c][7] = dn[7] * g1.w;
    } else {
#pragma unroll
      for (int a = 0; a < 8; ++a) scfsh[i][c][a] = 0.f;
    }
  }
  __syncthreads();

  // phase 1
  int c2 = t & 127, yg = t >> 7;
  int h = c2 >> 4;
  float s0r[16];
#pragma unroll
  for (int n = 0; n < 16; ++n) s0r[n] = s0[h * 16 + n];
  const bf16* vsb = vraw + (long)b * (4096 * 256);
  const bf16* rp[4];
#pragma unroll
  for (int i = 0; i < 4; ++i) {
    int r = 2 * x + i - 1;
    int rc = min(max(r, 0), 63);            // clamp addr; scfsh==0 kills coef
    rp[i] = vsb + (long)rc * 64 * 256 + 2 * c2;
  }

#define LOADYI(U, y_)                                                        \
  {                                                                          \
    _Pragma("unroll") for (int i_ = 0; i_ < 4; ++i_) {                       \
      _Pragma("unroll") for (int j_ = 0; j_ < 4; ++j_) {                     \
        int c_ = 2 * (y_) + j_ - 1;                                          \
        int cc_ = min(max(c_, 0), 63);                                       \
        U[i_][j_] = *(const unsigned*)(rp[i_] + (long)cc_ * 256);            \
      }                                                                      \
    }                                                                        \
  }
#define COMPYI(U, y_)                                                        \
  {                                                                          \
    float p0 = 0.f, p1 = 0.f;                                                \
    _Pragma("unroll") for (int i_ = 0; i_ < 4; ++i_) {                       \
      _Pragma("unroll") for (int j_ = 0; j_ < 4; ++j_) {                     \
        int c_ = 2 * (y_) + j_ - 1;                                          \
        float coef = (c_ >= 0 && c_ < 64)                                    \
                         ? s0r[i_ * 4 + j_] * scfsh[i_][c_][h]               \
                         : 0.f;                                              \
        unsigned u_ = U[i_][j_];                                             \
        p0 += coef * bf2f((unsigned short)(u_ & 0xffff));                    \
        p1 += coef * bf2f((unsigned short)(u_ >> 16));                       \
      }                                                                      \
    }                                                                        \
    *(unsigned*)&opsh[y_][2 * c2] = pk2(p0, p1);                             \
  }

  {
    unsigned UA[4][4], UB[4][4];
    LOADYI(UA, yg);                        // yi=0 -> y = yg
#pragma unroll
    for (int yp = 0; yp < 8; ++yp) {
      int yA = (2 * yp) * 2 + yg;
      int yB = (2 * yp + 1) * 2 + yg;
      LOADYI(UB, yB);                      // in flight during A's FMA chain
      COMPYI(UA, yA);
      if (yp < 7) {
        int yA2 = (2 * yp + 2) * 2 + yg;
        LOADYI(UA, yA2);                   // in flight during B's FMA chain
      }
      COMPYI(UB, yB);
    }
  }
#undef LOADYI
#undef COMPYI
  __syncthreads();

  // phase 2: MFMA  out[32x256] = op @ wf + b
  int wave = t >> 6, lane = t & 63;
  int n0 = wave * 64;
  int lm = lane & 15, q = lane >> 4;
  f32x4 acc[2][4];
#pragma unroll
  for (int mf = 0; mf < 2; ++mf)
#pragma unroll
    for (int nf = 0; nf < 4; ++nf) acc[mf][nf] = (f32x4){0.f, 0.f, 0.f, 0.f};
  const bf16* brow = wfT + (n0 + lm) * 256;
#pragma unroll
  for (int ks = 0; ks < 8; ++ks) {
    int kof = ks * 32 + q * 8;
    bf16x8 a0 = *(const bf16x8*)(&opsh[lm][kof]);
    bf16x8 a1 = *(const bf16x8*)(&opsh[16 + lm][kof]);
#pragma unroll
    for (int nf = 0; nf < 4; ++nf) {
      bf16x8 bb = *(const bf16x8*)(brow + nf * 4096 + kof);
      acc[0][nf] = __builtin_amdgcn_mfma_f32_16x16x32_bf16(a0, bb, acc[0][nf], 0, 0, 0);
      acc[1][nf] = __builtin_amdgcn_mfma_f32_16x16x32_bf16(a1, bb, acc[1][nf], 0, 0, 0);
    }
  }
  long out0 = (long)bx * 32 * 256;
#pragma unroll
  for (int nf = 0; nf < 4; ++nf) {
    int col = n0 + nf * 16 + lm;
    float wb = wf_b[col];
#pragma unroll
    for (int mf = 0; mf < 2; ++mf) {
#pragma unroll
      for (int r = 0; r < 4; ++r) {
        int row = mf * 16 + q * 4 + r;
        out[out0 + row * 256 + col] = acc[mf][nf][r] + wb;
      }
    }
  }
}

// ---------------------------------------------------------------------------
// Workspace (float offsets): s0 0 | qv 128 | denom 256 | gbuf 1024 (+1M)
// wvT @1049600 (+32768) | wfT @1082368 (+32768) | wgkT @1115136 (+2048)
// vraw(bf16) @1117184 (+16.7M f-equiv). Total ~71.6 MB.
// ---------------------------------------------------------------------------
extern "C" void kernel_launch(void* const* d_in, const int* in_sizes, int n_in,
                              void* d_out, int out_size, void* d_ws, size_t ws_size,
                              hipStream_t stream) {
  const float* inps  = (const float*)d_in[0];
  const float* emb   = (const float*)d_in[1];
  const float* wkq_w = (const float*)d_in[2];
  const float* wkq_b = (const float*)d_in[3];
  const float* wv_w  = (const float*)d_in[4];
  const float* wv_b  = (const float*)d_in[5];
  const float* wgq_w = (const float*)d_in[6];
  const float* wgq_b = (const float*)d_in[7];
  const float* wgk_w = (const float*)d_in[8];
  const float* wgk_b = (const float*)d_in[9];
  const float* wf_w  = (const float*)d_in[10];
  const float* wf_b  = (const float*)d_in[11];

  float* wsf   = (float*)d_ws;
  float* s0f   = wsf;
  float* qvf   = wsf + 128;
  float* denom = wsf + 256;
  float* gbuf  = wsf + 1024;
  bf16*  wvT   = (bf16*)(wsf + 1049600);
  bf16*  wfT   = (bf16*)(wsf + 1082368);
  bf16*  wgkT  = (bf16*)(wsf + 1115136);
  bf16*  vraw  = (bf16*)(wsf + 1117184);
  float* outp  = (float*)d_out;

  hipMemsetAsync((void*)denom, 0, 1024, stream);
  k1_setup<<<1, 256, 0, stream>>>(emb, wkq_w, wkq_b, wgq_w, wgq_b, s0f, qvf);
  prep<<<33, 256, 0, stream>>>(wv_w, wf_w, wgk_w, wvT, wfT, wgkT);
  kA<<<PIX_ / 32, 256, 0, stream>>>(inps, wvT, wgkT, wv_b, wgk_b, qvf,
                                    vraw, gbuf, denom);
  kB<<<OUTPIX_ / 32, 256, 0, stream>>>(vraw, s0f, gbuf, denom, wfT, wf_b, outp);
}

// Round 7
// 335.332 us; speedup vs baseline: 1.2445x; 1.0108x over previous
//
#include <hip/hip_runtime.h>
#include <hip/hip_bf16.h>

// Problem constants
#define B_    32
#define H_    64
#define W_    64
#define C_    256
#define NH_   8
#define N_    16
#define PIX_  (B_*H_*W_)     // 131072
#define OUTPIX_ (B_*32*32)   // 32768

typedef __hip_bfloat16 bf16;
typedef __attribute__((ext_vector_type(8))) short bf16x8;   // 8 bf16 = 4 VGPR
typedef __attribute__((ext_vector_type(4))) float f32x4;

__device__ __forceinline__ float bf2f(unsigned short u) {
  union { unsigned int i; float f; } v; v.i = ((unsigned int)u) << 16; return v.f;
}
__device__ __forceinline__ unsigned pk2(float a, float b) {
  union { __hip_bfloat162 h2; unsigned u; } c;
  c.h2 = __float22bfloat162_rn(make_float2(a, b));
  return c.u;
}

// ---------------------------------------------------------------------------
// K1: s0[8][16] (softmax row 0 of logits) and qv[8]. One block.
// ---------------------------------------------------------------------------
__global__ __launch_bounds__(256) void k1_setup(
    const float* __restrict__ emb, const float* __restrict__ wkq_w,
    const float* __restrict__ wkq_b, const float* __restrict__ wgq_w,
    const float* __restrict__ wgq_b,
    float* __restrict__ s0, float* __restrict__ qv) {
  __shared__ float lq[128];
  __shared__ float lk[16][8];
  int t = threadIdx.x;
  if (t < 128) {
    float acc = wkq_b[128 + t];
    for (int e = 0; e < 128; ++e) acc += emb[e] * wkq_w[e * 256 + 128 + t];
    lq[t] = acc;
  } else {
    int idx = t - 128; int j = idx >> 3, h = idx & 7;
    float acc = wkq_b[h * 16];
    for (int e = 0; e < 128; ++e) acc += emb[j * 128 + e] * wkq_w[e * 256 + h * 16];
    lk[j][h] = acc;
  }
  __syncthreads();
  if (t < 8) {
    float l[16]; float m = -1e30f;
    for (int j = 0; j < 16; ++j) { l[j] = lq[t * 16 + j] + lk[j][t]; m = fmaxf(m, l[j]); }
    float s = 0.f;
    for (int j = 0; j < 16; ++j) { l[j] = expf(l[j] - m); s += l[j]; }
    float inv = 1.f / s;
    for (int j = 0; j < 16; ++j) s0[t * 16 + j] = l[j] * inv;
    float acc = wgq_b[t];
    for (int e = 0; e < 128; ++e) acc += emb[14 * 128 + e] * wgq_w[e * 8 + t];
    qv[t] = acc;
  }
}

// ---------------------------------------------------------------------------
// prep: LDS-tiled transposes to bf16.
//   blocks 0..15 : wvT[n][k]  = wv[k][n]   (64x64 tiles)
//   blocks 16..31: wfT[n][k]  = wf[k][n]
//   block  32    : wgkT[a][k] = wgk[k][a]  (rows 8..15 zero)
// ---------------------------------------------------------------------------
__global__ __launch_bounds__(256) void prep(
    const float* __restrict__ wv, const float* __restrict__ wf,
    const float* __restrict__ wgk,
    bf16* __restrict__ wvT, bf16* __restrict__ wfT, bf16* __restrict__ wgkT) {
  int bid = blockIdx.x, t = threadIdx.x;
  if (bid < 32) {
    __shared__ unsigned short tile[64][72];
    const float* src = (bid < 16) ? wv : wf;
    bf16* dst = (bid < 16) ? wvT : wfT;
    int tb = bid & 15, tr = tb >> 2, tc = tb & 3;
#pragma unroll
    for (int it = 0; it < 16; ++it) {
      int idx = it * 256 + t, row = idx >> 6, col = idx & 63;
      bf16 h = __float2bfloat16(src[(tr * 64 + row) * 256 + tc * 64 + col]);
      tile[row][col] = *(unsigned short*)&h;
    }
    __syncthreads();
#pragma unroll
    for (int it = 0; it < 16; ++it) {
      int idx = it * 256 + t, row = idx >> 6, col = idx & 63;
      dst[(tc * 64 + row) * 256 + (tr * 64 + col)] = *(bf16*)&tile[col][row];
    }
  } else {
    __shared__ float g[2048];
#pragma unroll
    for (int it = 0; it < 8; ++it) g[it * 256 + t] = wgk[it * 256 + t];
    __syncthreads();
#pragma unroll
    for (int it = 0; it < 16; ++it) {
      int idx = it * 256 + t, a = idx >> 8, k = idx & 255;
      float v = (a < 8) ? g[k * 8 + a] : 0.f;
      wgkT[a * 256 + k] = __float2bfloat16(v);
    }
  }
}

// ---------------------------------------------------------------------------
// kA v8 (B-stationary in registers):
//   vraw = inps @ wv + wv_b          (bf16 out, no scale yet)
//   g    = relu(qv + inps @ wgk + b) -> gbuf; denom += sum(g)
// 4096 blocks x 32 px, 256 threads (4 waves, M32xN64 each). Each wave loads
// its ENTIRE B-slice (64 cols x K=256 = 32 bf16x8 frags = 128 VGPR) once at
// block start, before A staging: one 40-load latency event (FIFO vmcnt
// drains B with the A wait). The K-loop is then pure ds_read+MFMA with all
// B indices compile-time-constant -> the allocator MUST keep B resident
// (v6/v7 failure: in-loop batches get re-materialized; VGPR stayed 56).
// Falsifiable signature: VGPR_Count >= 190. launch_bounds(256,2) grants 256.
// ---------------------------------------------------------------------------
__global__ __launch_bounds__(256, 2) void kA(
    const float* __restrict__ inps, const bf16* __restrict__ wvT,
    const bf16* __restrict__ wgkT, const float* __restrict__ wv_b,
    const float* __restrict__ wgk_b, const float* __restrict__ qv,
    bf16* __restrict__ vraw, float* __restrict__ gbuf,
    float* __restrict__ denom) {
  // [2 K-halves][32 rows][128 bf16 + 8 pad] = 17408 B
  __shared__ __align__(16) unsigned short ldsA[2][32][136];
  __shared__ float sden[8];
  __shared__ float qvb_s[8];
  int t = threadIdx.x;
  const long pix0 = (long)blockIdx.x * 32;
  if (t < 8) { sden[t] = 0.f; qvb_s[t] = qv[t] + wgk_b[t]; }

  int wave = t >> 6, lane = t & 63;
  int nw = wave;                    // 4 waves: one M32xN64 tile each
  int n0 = nw * 64;
  int lm = lane & 15, q = lane >> 4;
  bool gatew = (nw == 0);
  const bf16* brow = wvT + (n0 + lm) * 256;
  const bf16* grow = wgkT + lm * 256;

  // ---- B-slice into registers: 32 frags (128 VGPR) + 8 gate frags -------
  bf16x8 Bv[4][8];                  // [nf][ks], indices compile-time only
#pragma unroll
  for (int nf = 0; nf < 4; ++nf)
#pragma unroll
    for (int ks = 0; ks < 8; ++ks)
      Bv[nf][ks] = *(const bf16x8*)(brow + nf * 4096 + ks * 32 + q * 8);
  bf16x8 Bg[8];
  if (gatew) {
#pragma unroll
    for (int ks = 0; ks < 8; ++ks)
      Bg[ks] = *(const bf16x8*)(grow + ks * 32 + q * 8);
  }

  // ---- A staging: 32x256 fp32 -> bf16 LDS (8 float4/thread) -------------
  {
    const float* src = inps + pix0 * 256;
    float4 st[8];
#pragma unroll
    for (int it = 0; it < 8; ++it) {
      int idx = it * 256 + t;
      int row = idx >> 6, c4 = (idx & 63) << 2;
      st[it] = *(const float4*)(src + row * 256 + c4);
    }
    __builtin_amdgcn_sched_barrier(0);   // B+A all issued before any use
#pragma unroll
    for (int it = 0; it < 8; ++it) {
      int idx = it * 256 + t;
      int row = idx >> 6, c4 = (idx & 63) << 2;
      *(uint2*)&ldsA[c4 >> 7][row][c4 & 127] =
          make_uint2(pk2(st[it].x, st[it].y), pk2(st[it].z, st[it].w));
    }
  }
  __syncthreads();

  f32x4 acc[2][4], accg[2];
#pragma unroll
  for (int mf = 0; mf < 2; ++mf) {
    accg[mf] = (f32x4){0.f, 0.f, 0.f, 0.f};
#pragma unroll
    for (int nf = 0; nf < 4; ++nf) acc[mf][nf] = (f32x4){0.f, 0.f, 0.f, 0.f};
  }

  // ---- K-loop: pure LDS reads + MFMA (B already resident) ---------------
#pragma unroll
  for (int ks = 0; ks < 8; ++ks) {
    int h = ks >> 2;
    int kof = (ks & 3) * 32 + q * 8;
    bf16x8 a0 = *(const bf16x8*)(&ldsA[h][lm][kof]);
    bf16x8 a1 = *(const bf16x8*)(&ldsA[h][16 + lm][kof]);
#pragma unroll
    for (int nf = 0; nf < 4; ++nf) {
      acc[0][nf] = __builtin_amdgcn_mfma_f32_16x16x32_bf16(a0, Bv[nf][ks], acc[0][nf], 0, 0, 0);
      acc[1][nf] = __builtin_amdgcn_mfma_f32_16x16x32_bf16(a1, Bv[nf][ks], acc[1][nf], 0, 0, 0);
    }
    if (gatew) {
      accg[0] = __builtin_amdgcn_mfma_f32_16x16x32_bf16(a0, Bg[ks], accg[0], 0, 0, 0);
      accg[1] = __builtin_amdgcn_mfma_f32_16x16x32_bf16(a1, Bg[ks], accg[1], 0, 0, 0);
    }
  }

  // vraw epilogue (bias only; scale applied in kB)
#pragma unroll
  for (int nf = 0; nf < 4; ++nf) {
    int col = n0 + nf * 16 + lm;
    float wb = wv_b[col];
#pragma unroll
    for (int mf = 0; mf < 2; ++mf) {
#pragma unroll
      for (int r = 0; r < 4; ++r) {
        int rl = mf * 16 + q * 4 + r;
        vraw[(pix0 + rl) * 256 + col] = __float2bfloat16(acc[mf][nf][r] + wb);
      }
    }
  }

  // gate epilogue
  if (gatew) {
    float part = 0.f;
    if (lm < 8) {
#pragma unroll
      for (int mf = 0; mf < 2; ++mf) {
#pragma unroll
        for (int r = 0; r < 4; ++r) {
          int rl = mf * 16 + q * 4 + r;
          float gg = fmaxf(qvb_s[lm] + accg[mf][r], 0.f);
          gbuf[(pix0 + rl) * 8 + lm] = gg;
          part += gg;
        }
      }
    }
    part += __shfl_xor(part, 16, 64);
    part += __shfl_xor(part, 32, 64);
    if (lane < 16 && lm < 8) atomicAdd(&sden[lm], part);
  }
  __syncthreads();
  if (t < 8) atomicAdd(&denom[(int)(blockIdx.x >> 7) * 8 + t], sden[t]);
}

// ---------------------------------------------------------------------------
// kB v6 (fused scale + patch gather + final GEMM). Block = (b,x) row, 256 thr.
// Phase 0: stage scf[i][c][a] = 4096/(denom+eps)*g (float4 gbuf reads).
// Phase 1: op[y][ch] = sum_taps (s0*scf) * vraw, double-buffered tap prefetch.
// Phase 2: out = op @ wf + wf_b via MFMA (wfT in L2).
// ---------------------------------------------------------------------------
__global__ __launch_bounds__(256) void kB(
    const bf16* __restrict__ vraw, const float* __restrict__ s0,
    const float* __restrict__ gbuf, const float* __restrict__ denom,
    const bf16* __restrict__ wfT, const float* __restrict__ wf_b,
    float* __restrict__ out) {
  __shared__ float scfsh[4][64][8];                      // 8 KB
  __shared__ __align__(16) unsigned short opsh[32][264]; // bf16 bits
  int t = threadIdx.x;
  int bx = blockIdx.x, b = bx >> 5, x = bx & 31;

  { // phase 0
    int i = t >> 6, c = t & 63;
    int r = 2 * x + i - 1;
    if (r >= 0 && r < 64) {
      float dn[8];
#pragma unroll
      for (int a = 0; a < 8; ++a) dn[a] = 4096.0f / (denom[b * 8 + a] + 1e-6f);
      long p = (long)b * 4096 + r * 64 + c;
      const float4* gp = (const float4*)&gbuf[p * 8];
      float4 g0 = gp[0], g1 = gp[1];
      scfsh[i][c][0] = dn[0] * g0.x;
      scfsh[i][c][1] = dn[1] * g0.y;
      scfsh[i][c][2] = dn[2] * g0.z;
      scfsh[i][c][3] = dn[3] * g0.w;
      scfsh[i][c][4] = dn[4] * g1.x;
      scfsh[i][c][5] = dn[5] * g1.y;
      scfsh[i][c][6] = dn[6] * g1.z;
      scfsh[i][c][7] = dn[7] * g1.w;
    } else {
#pragma unroll
      for (int a = 0; a < 8; ++a) scfsh[i][c][a] = 0.f;
    }
  }
  __syncthreads();

  // phase 1
  int c2 = t & 127, yg = t >> 7;
  int h = c2 >> 4;
  float s0r[16];
#pragma unroll
  for (int n = 0; n < 16; ++n) s0r[n] = s0[h * 16 + n];
  const bf16* vsb = vraw + (long)b * (4096 * 256);
  const bf16* rp[4];
#pragma unroll
  for (int i = 0; i < 4; ++i) {
    int r = 2 * x + i - 1;
    int rc = min(max(r, 0), 63);            // clamp addr; scfsh==0 kills coef
    rp[i] = vsb + (long)rc * 64 * 256 + 2 * c2;
  }

#define LOADYI(U, y_)                                                        \
  {                                                                          \
    _Pragma("unroll") for (int i_ = 0; i_ < 4; ++i_) {                       \
      _Pragma("unroll") for (int j_ = 0; j_ < 4; ++j_) {                     \
        int c_ = 2 * (y_) + j_ - 1;                                          \
        int cc_ = min(max(c_, 0), 63);                                       \
        U[i_][j_] = *(const unsigned*)(rp[i_] + (long)cc_ * 256);            \
      }                                                                      \
    }                                                                        \
  }
#define COMPYI(U, y_)                                                        \
  {                                                                          \
    float p0 = 0.f, p1 = 0.f;                                                \
    _Pragma("unroll") for (int i_ = 0; i_ < 4; ++i_) {                       \
      _Pragma("unroll") for (int j_ = 0; j_ < 4; ++j_) {                     \
        int c_ = 2 * (y_) + j_ - 1;                                          \
        float coef = (c_ >= 0 && c_ < 64)                                    \
                         ? s0r[i_ * 4 + j_] * scfsh[i_][c_][h]               \
                         : 0.f;                                              \
        unsigned u_ = U[i_][j_];                                             \
        p0 += coef * bf2f((unsigned short)(u_ & 0xffff));                    \
        p1 += coef * bf2f((unsigned short)(u_ >> 16));                       \
      }                                                                      \
    }                                                                        \
    *(unsigned*)&opsh[y_][2 * c2] = pk2(p0, p1);                             \
  }

  {
    unsigned UA[4][4], UB[4][4];
    LOADYI(UA, yg);                        // yi=0 -> y = yg
#pragma unroll
    for (int yp = 0; yp < 8; ++yp) {
      int yA = (2 * yp) * 2 + yg;
      int yB = (2 * yp + 1) * 2 + yg;
      LOADYI(UB, yB);                      // in flight during A's FMA chain
      COMPYI(UA, yA);
      if (yp < 7) {
        int yA2 = (2 * yp + 2) * 2 + yg;
        LOADYI(UA, yA2);                   // in flight during B's FMA chain
      }
      COMPYI(UB, yB);
    }
  }
#undef LOADYI
#undef COMPYI
  __syncthreads();

  // phase 2: MFMA  out[32x256] = op @ wf + b
  int wave = t >> 6, lane = t & 63;
  int n0 = wave * 64;
  int lm = lane & 15, q = lane >> 4;
  f32x4 acc[2][4];
#pragma unroll
  for (int mf = 0; mf < 2; ++mf)
#pragma unroll
    for (int nf = 0; nf < 4; ++nf) acc[mf][nf] = (f32x4){0.f, 0.f, 0.f, 0.f};
  const bf16* brow = wfT + (n0 + lm) * 256;
#pragma unroll
  for (int ks = 0; ks < 8; ++ks) {
    int kof = ks * 32 + q * 8;
    bf16x8 a0 = *(const bf16x8*)(&opsh[lm][kof]);
    bf16x8 a1 = *(const bf16x8*)(&opsh[16 + lm][kof]);
#pragma unroll
    for (int nf = 0; nf < 4; ++nf) {
      bf16x8 bb = *(const bf16x8*)(brow + nf * 4096 + kof);
      acc[0][nf] = __builtin_amdgcn_mfma_f32_16x16x32_bf16(a0, bb, acc[0][nf], 0, 0, 0);
      acc[1][nf] = __builtin_amdgcn_mfma_f32_16x16x32_bf16(a1, bb, acc[1][nf], 0, 0, 0);
    }
  }
  long out0 = (long)bx * 32 * 256;
#pragma unroll
  for (int nf = 0; nf < 4; ++nf) {
    int col = n0 + nf * 16 + lm;
    float wb = wf_b[col];
#pragma unroll
    for (int mf = 0; mf < 2; ++mf) {
#pragma unroll
      for (int r = 0; r < 4; ++r) {
        int row = mf * 16 + q * 4 + r;
        out[out0 + row * 256 + col] = acc[mf][nf][r] + wb;
      }
    }
  }
}

// ---------------------------------------------------------------------------
// Workspace (float offsets): s0 0 | qv 128 | denom 256 | gbuf 1024 (+1M)
// wvT @1049600 (+32768) | wfT @1082368 (+32768) | wgkT @1115136 (+2048)
// vraw(bf16) @1117184 (+16.7M f-equiv). Total ~71.6 MB.
// ---------------------------------------------------------------------------
extern "C" void kernel_launch(void* const* d_in, const int* in_sizes, int n_in,
                              void* d_out, int out_size, void* d_ws, size_t ws_size,
                              hipStream_t stream) {
  const float* inps  = (const float*)d_in[0];
  const float* emb   = (const float*)d_in[1];
  const float* wkq_w = (const float*)d_in[2];
  const float* wkq_b = (const float*)d_in[3];
  const float* wv_w  = (const float*)d_in[4];
  const float* wv_b  = (const float*)d_in[5];
  const float* wgq_w = (const float*)d_in[6];
  const float* wgq_b = (const float*)d_in[7];
  const float* wgk_w = (const float*)d_in[8];
  const float* wgk_b = (const float*)d_in[9];
  const float* wf_w  = (const float*)d_in[10];
  const float* wf_b  = (const float*)d_in[11];

  float* wsf   = (float*)d_ws;
  float* s0f   = wsf;
  float* qvf   = wsf + 128;
  float* denom = wsf + 256;
  float* gbuf  = wsf + 1024;
  bf16*  wvT   = (bf16*)(wsf + 1049600);
  bf16*  wfT   = (bf16*)(wsf + 1082368);
  bf16*  wgkT  = (bf16*)(wsf + 1115136);
  bf16*  vraw  = (bf16*)(wsf + 1117184);
  float* outp  = (float*)d_out;

  hipMemsetAsync((void*)denom, 0, 1024, stream);
  k1_setup<<<1, 256, 0, stream>>>(emb, wkq_w, wkq_b, wgq_w, wgq_b, s0f, qvf);
  prep<<<33, 256, 0, stream>>>(wv_w, wf_w, wgk_w, wvT, wfT, wgkT);
  kA<<<PIX_ / 32, 256, 0, stream>>>(inps, wvT, wgkT, wv_b, wgk_b, qvf,
                                    vraw, gbuf, denom);
  kB<<<OUTPIX_ / 32, 256, 0, stream>>>(vraw, s0f, gbuf, denom, wfT, wf_b, outp);
}